// Round 1
// baseline (404.410 us; speedup 1.0000x reference)
//
#include <hip/hip_runtime.h>
#include <stdint.h>

// OHEM MSE loss: exact k-th-largest selection via 2-round radix select on
// float bit patterns (loss >= 0 so uint ordering == float ordering).
//
// norm_term = 8*1024*1024 = 2^23 exactly -> scale by 0x1p-23f is exact and
// reproduces reference rounding bit-for-bit.

#define H2_BITS 17            // low bits resolved in round 2
#define H1_SIZE 32768         // 2^15 bins (top 15 bits)
#define H2_SIZE 131072        // 2^17 bins (low 17 bits)
#define SHARDS 64

// ws layout (bytes):
//   0       u32 hist1[32768]    (128 KB)
//   131072  u32 hist2[131072]   (512 KB)
//   655360  u32 meta[16]: [0]=b [1]=kprime [2]=thr_bits [3]=overflow
//                         [4]=cnt_above [5]=cnt_cand
//   655424  double sums[2]: [0]=sum_above [1]=sum_cand
//   655488  u32 shard_cnt[64]
//   786432  uint2 cand[SHARDS][cap_per_shard]  {bits, weight_bits}
#define OFF_H2   131072
#define OFF_META 655360
#define OFF_SUMS 655424
#define OFF_SHC  655488
#define OFF_CAND 786432

__global__ __launch_bounds__(256) void k_zero(uint32_t* ws, int n) {
    int i = blockIdx.x * 256 + threadIdx.x;
    if (i < n) ws[i] = 0;
}

// Pass 1: histogram of top-15 bits. Packed 2xu16 per u32 in LDS (64 KB ->
// 2 blocks/CU). Per-block element count 32768 <= 65535 so u16 never carries.
__global__ __launch_bounds__(1024) void k_hist1(
    const float4* __restrict__ p, const float4* __restrict__ t,
    uint32_t* __restrict__ hist1, int n4)
{
    __shared__ uint32_t lh[H1_SIZE / 2];
    for (int i = threadIdx.x; i < H1_SIZE / 2; i += 1024) lh[i] = 0;
    __syncthreads();
    const int stride = gridDim.x * 1024;
    for (int i = blockIdx.x * 1024 + threadIdx.x; i < n4; i += stride) {
        float4 pv = p[i], tv = t[i];
        float d0 = pv.x - tv.x, d1 = pv.y - tv.y, d2 = pv.z - tv.z, d3 = pv.w - tv.w;
        uint32_t b0 = __float_as_uint(d0 * d0 * 0x1p-23f) >> H2_BITS;
        uint32_t b1 = __float_as_uint(d1 * d1 * 0x1p-23f) >> H2_BITS;
        uint32_t b2 = __float_as_uint(d2 * d2 * 0x1p-23f) >> H2_BITS;
        uint32_t b3 = __float_as_uint(d3 * d3 * 0x1p-23f) >> H2_BITS;
        atomicAdd(&lh[b0 >> 1], 1u << ((b0 & 1) * 16));
        atomicAdd(&lh[b1 >> 1], 1u << ((b1 & 1) * 16));
        atomicAdd(&lh[b2 >> 1], 1u << ((b2 & 1) * 16));
        atomicAdd(&lh[b3 >> 1], 1u << ((b3 & 1) * 16));
    }
    __syncthreads();
    for (int i = threadIdx.x; i < H1_SIZE / 2; i += 1024) {
        uint32_t v = lh[i];
        uint32_t c0 = v & 0xFFFFu, c1 = v >> 16;
        if (c0) atomicAdd(&hist1[2 * i], c0);
        if (c1) atomicAdd(&hist1[2 * i + 1], c1);
    }
}

// Find bin containing the k-th largest (scan from top). 1 block, 1024 thr.
__global__ __launch_bounds__(1024) void k_scan1(
    const uint32_t* __restrict__ hist1, const int* __restrict__ min_kept,
    uint32_t* __restrict__ meta)
{
    __shared__ uint32_t psum[1024];
    __shared__ uint32_t gsuf[64];
    const int t = threadIdx.x;
    const uint32_t k = (uint32_t)(*min_kept);
    const int per = H1_SIZE / 1024;                 // 32 bins/thread
    const int base = t * per;
    uint32_t s = 0;
    #pragma unroll
    for (int i = 0; i < per; i++) s += hist1[base + i];
    psum[t] = s;
    __syncthreads();
    if (t < 64) {                                    // wave 0: 64 groups of 16
        uint32_t g = 0;
        for (int i = 0; i < 16; i++) g += psum[t * 16 + i];
        uint32_t v = g;
        #pragma unroll
        for (int off = 1; off < 64; off <<= 1) {
            uint32_t o = __shfl_down(v, off);
            if (t + off < 64) v += o;
        }
        gsuf[t] = v;                                 // sum of groups t..63
    }
    __syncthreads();
    const int g = t >> 4;
    uint32_t cum = (g < 63) ? gsuf[g + 1] : 0;       // groups strictly above
    const int gend = g * 16 + 15;
    for (int j = t + 1; j <= gend; j++) cum += psum[j];
    // cum = count of elements in bins above this thread's segment
    if (cum < k && k <= cum + psum[t]) {
        uint32_t c = cum;
        for (int i = per - 1; i >= 0; i--) {
            uint32_t h = hist1[base + i];
            c += h;
            if (c >= k) {
                meta[0] = (uint32_t)(base + i);      // coarse bin b
                meta[1] = k - (c - h);               // rank within bin (1-idx)
                break;
            }
        }
    }
}

// Main pass: accumulate sum/count for hi>b; histogram+compact hi==b.
__global__ __launch_bounds__(256) void k_main(
    const float4* __restrict__ p, const float4* __restrict__ t,
    const float4* __restrict__ w,
    uint32_t* meta, uint32_t* __restrict__ hist2,
    double* __restrict__ sums, uint32_t* __restrict__ shard_cnt,
    uint2* __restrict__ cand, uint32_t cap_per_shard, int n4)
{
    const uint32_t b = meta[0];
    double lsum = 0.0;
    uint32_t lcnt = 0;
    const int shard = blockIdx.x & (SHARDS - 1);
    uint32_t* my_cnt = &shard_cnt[shard];
    uint2* my_cand = cand + (size_t)shard * cap_per_shard;
    const int stride = gridDim.x * 256;
    for (int i = blockIdx.x * 256 + threadIdx.x; i < n4; i += stride) {
        float4 pv = p[i], tv = t[i], wv = w[i];
        float pd[4] = {pv.x - tv.x, pv.y - tv.y, pv.z - tv.z, pv.w - tv.w};
        float wa[4] = {wv.x, wv.y, wv.z, wv.w};
        #pragma unroll
        for (int c = 0; c < 4; c++) {
            float loss = pd[c] * pd[c] * 0x1p-23f;
            uint32_t bits = __float_as_uint(loss);
            uint32_t hi = bits >> H2_BITS;
            if (hi > b) {
                lcnt++;
                lsum += (double)(wa[c] * loss);
            } else if (hi == b) {
                atomicAdd(&hist2[bits & (H2_SIZE - 1)], 1u);
                uint32_t idx = atomicAdd(my_cnt, 1u);
                if (idx < cap_per_shard) {
                    my_cand[idx] = make_uint2(bits, __float_as_uint(wa[c]));
                } else {
                    meta[3] = 1u;                    // overflow -> fallback
                }
            }
        }
    }
    // block reduce (double sum + u32 count)
    #pragma unroll
    for (int off = 32; off; off >>= 1) {
        lsum += __shfl_down(lsum, off);
        lcnt += __shfl_down(lcnt, off);
    }
    __shared__ double sred[4];
    __shared__ uint32_t cred[4];
    const int wid = threadIdx.x >> 6, lane = threadIdx.x & 63;
    if (lane == 0) { sred[wid] = lsum; cred[wid] = lcnt; }
    __syncthreads();
    if (threadIdx.x == 0) {
        double bs = sred[0] + sred[1] + sred[2] + sred[3];
        uint32_t bc = cred[0] + cred[1] + cred[2] + cred[3];
        atomicAdd(&sums[0], bs);
        atomicAdd(&meta[4], bc);
    }
}

// Resolve exact threshold bits within bin b.
__global__ __launch_bounds__(1024) void k_scan2(
    const uint32_t* __restrict__ hist2, uint32_t* meta)
{
    __shared__ uint32_t psum[1024];
    __shared__ uint32_t gsuf[64];
    const int t = threadIdx.x;
    const uint32_t k = meta[1];                      // rank within bin b
    const uint32_t b = meta[0];
    const int per = H2_SIZE / 1024;                  // 128 bins/thread
    const int base = t * per;
    uint32_t s = 0;
    for (int i = 0; i < per; i++) s += hist2[base + i];
    psum[t] = s;
    __syncthreads();
    if (t < 64) {
        uint32_t g = 0;
        for (int i = 0; i < 16; i++) g += psum[t * 16 + i];
        uint32_t v = g;
        #pragma unroll
        for (int off = 1; off < 64; off <<= 1) {
            uint32_t o = __shfl_down(v, off);
            if (t + off < 64) v += o;
        }
        gsuf[t] = v;
    }
    __syncthreads();
    const int g = t >> 4;
    uint32_t cum = (g < 63) ? gsuf[g + 1] : 0;
    const int gend = g * 16 + 15;
    for (int j = t + 1; j <= gend; j++) cum += psum[j];
    if (cum < k && k <= cum + psum[t]) {
        uint32_t c = cum;
        for (int i = per - 1; i >= 0; i--) {
            uint32_t h = hist2[base + i];
            c += h;
            if (c >= k) {
                meta[2] = (b << H2_BITS) | (uint32_t)(base + i);  // thr bits
                break;
            }
        }
    }
}

// Accumulate candidates strictly above threshold. Fallback: full re-pass if
// candidate buffers overflowed (never with this data; correctness guard).
__global__ __launch_bounds__(256) void k_cand(
    const float4* __restrict__ p, const float4* __restrict__ t,
    const float4* __restrict__ w,
    uint32_t* meta, const uint32_t* __restrict__ shard_cnt,
    const uint2* __restrict__ cand, uint32_t cap_per_shard,
    double* __restrict__ sums, int n4)
{
    const uint32_t thr = meta[2];
    const uint32_t overflow = meta[3];
    double lsum = 0.0;
    uint32_t lcnt = 0;
    if (!overflow) {
        for (int sdx = 0; sdx < SHARDS; sdx++) {
            uint32_t cnt = shard_cnt[sdx];
            if (cnt > cap_per_shard) cnt = cap_per_shard;
            const uint2* cs = cand + (size_t)sdx * cap_per_shard;
            for (uint32_t i = blockIdx.x * 256 + threadIdx.x; i < cnt;
                 i += gridDim.x * 256) {
                uint2 e = cs[i];
                if (e.x > thr) {
                    lcnt++;
                    lsum += (double)(__uint_as_float(e.y) * __uint_as_float(e.x));
                }
            }
        }
    } else {
        const uint32_t b = meta[0];
        const int stride = gridDim.x * 256;
        for (int i = blockIdx.x * 256 + threadIdx.x; i < n4; i += stride) {
            float4 pv = p[i], tv = t[i], wv = w[i];
            float pd[4] = {pv.x - tv.x, pv.y - tv.y, pv.z - tv.z, pv.w - tv.w};
            float wa[4] = {wv.x, wv.y, wv.z, wv.w};
            #pragma unroll
            for (int c = 0; c < 4; c++) {
                float loss = pd[c] * pd[c] * 0x1p-23f;
                uint32_t bits = __float_as_uint(loss);
                if ((bits >> H2_BITS) == b && bits > thr) {
                    lcnt++;
                    lsum += (double)(wa[c] * loss);
                }
            }
        }
    }
    #pragma unroll
    for (int off = 32; off; off >>= 1) {
        lsum += __shfl_down(lsum, off);
        lcnt += __shfl_down(lcnt, off);
    }
    __shared__ double sred[4];
    __shared__ uint32_t cred[4];
    const int wid = threadIdx.x >> 6, lane = threadIdx.x & 63;
    if (lane == 0) { sred[wid] = lsum; cred[wid] = lcnt; }
    __syncthreads();
    if (threadIdx.x == 0) {
        double bs = sred[0] + sred[1] + sred[2] + sred[3];
        uint32_t bc = cred[0] + cred[1] + cred[2] + cred[3];
        atomicAdd(&sums[1], bs);
        atomicAdd(&meta[5], bc);
    }
}

__global__ __launch_bounds__(64) void k_final(
    const double* __restrict__ sums, const uint32_t* __restrict__ meta,
    float* __restrict__ out)
{
    if (threadIdx.x == 0 && blockIdx.x == 0) {
        double s = sums[0] + sums[1];
        double c = (double)(meta[4] + meta[5]);
        out[0] = (float)(s / c);
    }
}

extern "C" void kernel_launch(void* const* d_in, const int* in_sizes, int n_in,
                              void* d_out, int out_size, void* d_ws, size_t ws_size,
                              hipStream_t stream) {
    const float* p = (const float*)d_in[0];
    const float* t = (const float*)d_in[1];
    const float* w = (const float*)d_in[2];
    const int* mk = (const int*)d_in[3];
    float* out = (float*)d_out;
    const int n = in_sizes[0];       // 16777216, divisible by 4
    const int n4 = n / 4;

    uint8_t* ws = (uint8_t*)d_ws;
    uint32_t* hist1 = (uint32_t*)ws;
    uint32_t* hist2 = (uint32_t*)(ws + OFF_H2);
    uint32_t* meta  = (uint32_t*)(ws + OFF_META);
    double*   sums  = (double*)(ws + OFF_SUMS);
    uint32_t* shcnt = (uint32_t*)(ws + OFF_SHC);
    uint2*    cand  = (uint2*)(ws + OFF_CAND);
    uint32_t cap_per_shard = 0;
    if (ws_size > OFF_CAND + SHARDS * 8) {
        cap_per_shard = (uint32_t)((ws_size - OFF_CAND) / (8 * SHARDS));
    }

    k_zero<<<(OFF_CAND / 4 + 255) / 256, 256, 0, stream>>>((uint32_t*)ws, OFF_CAND / 4);
    k_hist1<<<512, 1024, 0, stream>>>((const float4*)p, (const float4*)t, hist1, n4);
    k_scan1<<<1, 1024, 0, stream>>>(hist1, mk, meta);
    k_main<<<2048, 256, 0, stream>>>((const float4*)p, (const float4*)t,
                                     (const float4*)w, meta, hist2, sums, shcnt,
                                     cand, cap_per_shard, n4);
    k_scan2<<<1, 1024, 0, stream>>>(hist2, meta);
    k_cand<<<2048, 256, 0, stream>>>((const float4*)p, (const float4*)t,
                                     (const float4*)w, meta, shcnt, cand,
                                     cap_per_shard, sums, n4);
    k_final<<<1, 64, 0, stream>>>(sums, meta, out);
}

// Round 2
// 386.112 us; speedup vs baseline: 1.0474x; 1.0474x over previous
//
#include <hip/hip_runtime.h>
#include <stdint.h>

// OHEM MSE loss: exact k-th-largest selection via 2-round radix select on
// float bit patterns (loss >= 0 so uint ordering == float ordering).
// norm_term = 8*1024*1024 = 2^23 exactly -> *0x1p-23f is an exact pow2 scale.
//
// Round-2 changes: batched unrolled loads for MLP (VGPR was 16 -> serialized
// loads -> 1.5 TB/s), wave-aggregated candidate compaction, 2-copy hist1
// flush with stagger, memsetAsync instead of k_zero.

#define H2_BITS 17            // low bits resolved in round 2
#define H1_SIZE 32768         // 2^15 bins (top 15 bits)
#define H1_WORDS (H1_SIZE / 2)
#define H2_SIZE 131072        // 2^17 bins (low 17 bits)
#define SHARDS 64

// ws layout (bytes):
//   0       u32 hist1[2][32768]  (2 copies, 256 KB)
//   262144  u32 hist2[131072]    (512 KB)
//   786432  u32 meta[16]: [0]=b [1]=kprime [2]=thr_bits [3]=overflow
//                         [4]=cnt_above [5]=cnt_cand
//   786496  double sums[2]
//   786560  u32 shard_cnt[64]
//   786944  uint2 cand[SHARDS][cap_per_shard]
#define OFF_H2   262144
#define OFF_META 786432
#define OFF_SUMS 786496
#define OFF_SHC  786560
#define OFF_CAND 786944

__device__ __forceinline__ void hist_add4(uint32_t* lh, float4 pv, float4 tv) {
    float d0 = pv.x - tv.x, d1 = pv.y - tv.y, d2 = pv.z - tv.z, d3 = pv.w - tv.w;
    uint32_t b0 = __float_as_uint(d0 * d0 * 0x1p-23f) >> H2_BITS;
    uint32_t b1 = __float_as_uint(d1 * d1 * 0x1p-23f) >> H2_BITS;
    uint32_t b2 = __float_as_uint(d2 * d2 * 0x1p-23f) >> H2_BITS;
    uint32_t b3 = __float_as_uint(d3 * d3 * 0x1p-23f) >> H2_BITS;
    atomicAdd(&lh[b0 >> 1], 1u << ((b0 & 1) * 16));
    atomicAdd(&lh[b1 >> 1], 1u << ((b1 & 1) * 16));
    atomicAdd(&lh[b2 >> 1], 1u << ((b2 & 1) * 16));
    atomicAdd(&lh[b3 >> 1], 1u << ((b3 & 1) * 16));
}

// Pass 1: histogram of top-15 bits. Packed 2xu16 in LDS (64 KB -> 2 blk/CU).
// Per-block elements = 1024 thr * 8 f4 * 4 = 32768 <= 65535, u16 safe.
__global__ __launch_bounds__(1024) void k_hist1(
    const float4* __restrict__ p, const float4* __restrict__ t,
    uint32_t* __restrict__ hist1, int n4)
{
    __shared__ uint32_t lh[H1_WORDS];
    for (int j = threadIdx.x; j < H1_WORDS; j += 1024) lh[j] = 0;
    __syncthreads();
    const int S = gridDim.x * 1024;
    int i = blockIdx.x * 1024 + threadIdx.x;
    for (; i + 3 * S < n4; i += 4 * S) {
        float4 pv0 = p[i],         tv0 = t[i];
        float4 pv1 = p[i + S],     tv1 = t[i + S];
        float4 pv2 = p[i + 2 * S], tv2 = t[i + 2 * S];
        float4 pv3 = p[i + 3 * S], tv3 = t[i + 3 * S];
        hist_add4(lh, pv0, tv0);
        hist_add4(lh, pv1, tv1);
        hist_add4(lh, pv2, tv2);
        hist_add4(lh, pv3, tv3);
    }
    for (; i < n4; i += S) hist_add4(lh, p[i], t[i]);
    __syncthreads();
    // flush to one of 2 global copies, block-staggered start to spread L2
    uint32_t* dst = hist1 + (blockIdx.x & 1) * H1_SIZE;
    const uint32_t rot = (blockIdx.x >> 1) * 64;
    for (int jj = threadIdx.x; jj < H1_WORDS; jj += 1024) {
        int j = (int)((jj + rot) & (H1_WORDS - 1));
        uint32_t v = lh[j];
        uint32_t c0 = v & 0xFFFFu, c1 = v >> 16;
        if (c0) atomicAdd(&dst[2 * j], c0);
        if (c1) atomicAdd(&dst[2 * j + 1], c1);
    }
}

// Find bin containing the k-th largest (suffix scan from top). 1 block.
__global__ __launch_bounds__(1024) void k_scan1(
    const uint32_t* __restrict__ hist1, const int* __restrict__ min_kept,
    uint32_t* __restrict__ meta)
{
    __shared__ uint32_t psum[1024];
    __shared__ uint32_t gsuf[64];
    const int t = threadIdx.x;
    const uint32_t k = (uint32_t)(*min_kept);
    const uint32_t* h0 = hist1;
    const uint32_t* h1 = hist1 + H1_SIZE;
    const int per = H1_SIZE / 1024;                 // 32 bins/thread
    const int base = t * per;
    uint32_t s = 0;
    #pragma unroll
    for (int i = 0; i < per; i++) s += h0[base + i] + h1[base + i];
    psum[t] = s;
    __syncthreads();
    if (t < 64) {                                    // 64 groups of 16
        uint32_t g = 0;
        for (int i = 0; i < 16; i++) g += psum[t * 16 + i];
        uint32_t v = g;
        #pragma unroll
        for (int off = 1; off < 64; off <<= 1) {
            uint32_t o = __shfl_down(v, off);
            if (t + off < 64) v += o;
        }
        gsuf[t] = v;                                 // sum of groups t..63
    }
    __syncthreads();
    const int g = t >> 4;
    uint32_t cum = (g < 63) ? gsuf[g + 1] : 0;
    const int gend = g * 16 + 15;
    for (int j = t + 1; j <= gend; j++) cum += psum[j];
    if (cum < k && k <= cum + psum[t]) {
        uint32_t c = cum;
        for (int i = per - 1; i >= 0; i--) {
            uint32_t h = h0[base + i] + h1[base + i];
            c += h;
            if (c >= k) {
                meta[0] = (uint32_t)(base + i);      // coarse bin b
                meta[1] = k - (c - h);               // rank within bin (1-idx)
                break;
            }
        }
    }
}

// Main pass: accumulate for hi>b; wave-aggregated compact + hist2 for hi==b.
__global__ __launch_bounds__(256) void k_main(
    const float4* __restrict__ p, const float4* __restrict__ t,
    const float4* __restrict__ w,
    uint32_t* meta, uint32_t* __restrict__ hist2,
    double* __restrict__ sums, uint32_t* __restrict__ shard_cnt,
    uint2* __restrict__ cand, uint32_t cap_per_shard, int n4)
{
    const uint32_t b = meta[0];
    double lsum = 0.0;
    uint32_t lcnt = 0;
    const int shard = blockIdx.x & (SHARDS - 1);
    uint32_t* my_cnt = &shard_cnt[shard];
    uint2* my_cand = cand + (size_t)shard * cap_per_shard;
    const int lane = threadIdx.x & 63;

    auto proc = [&](float4 pv, float4 tv, float4 wv) {
        float d[4] = {pv.x - tv.x, pv.y - tv.y, pv.z - tv.z, pv.w - tv.w};
        float wa[4] = {wv.x, wv.y, wv.z, wv.w};
        #pragma unroll
        for (int c = 0; c < 4; c++) {
            float loss = d[c] * d[c] * 0x1p-23f;
            uint32_t bits = __float_as_uint(loss);
            uint32_t hi = bits >> H2_BITS;
            if (hi > b) {
                lcnt++;
                lsum += (double)(wa[c] * loss);
            }
            unsigned long long m = __ballot(hi == b);
            if (m) {
                if (hi == b) {
                    int pos = __popcll(m & ((1ull << lane) - 1ull));
                    int leader = __ffsll(m) - 1;
                    uint32_t base_ = 0;
                    if (lane == leader)
                        base_ = atomicAdd(my_cnt, (uint32_t)__popcll(m));
                    base_ = __shfl(base_, leader);
                    uint32_t idx = base_ + (uint32_t)pos;
                    if (idx < cap_per_shard)
                        my_cand[idx] = make_uint2(bits, __float_as_uint(wa[c]));
                    else
                        meta[3] = 1u;                // overflow -> fallback
                    atomicAdd(&hist2[bits & (H2_SIZE - 1)], 1u);
                }
            }
        }
    };

    const int S = gridDim.x * 256;
    int i = blockIdx.x * 256 + threadIdx.x;
    for (; i + S < n4; i += 2 * S) {
        float4 pv0 = p[i],     tv0 = t[i],     wv0 = w[i];
        float4 pv1 = p[i + S], tv1 = t[i + S], wv1 = w[i + S];
        proc(pv0, tv0, wv0);
        proc(pv1, tv1, wv1);
    }
    for (; i < n4; i += S) proc(p[i], t[i], w[i]);

    #pragma unroll
    for (int off = 32; off; off >>= 1) {
        lsum += __shfl_down(lsum, off);
        lcnt += __shfl_down(lcnt, off);
    }
    __shared__ double sred[4];
    __shared__ uint32_t cred[4];
    const int wid = threadIdx.x >> 6;
    if (lane == 0) { sred[wid] = lsum; cred[wid] = lcnt; }
    __syncthreads();
    if (threadIdx.x == 0) {
        double bs = sred[0] + sred[1] + sred[2] + sred[3];
        uint32_t bc = cred[0] + cred[1] + cred[2] + cred[3];
        atomicAdd(&sums[0], bs);
        atomicAdd(&meta[4], bc);
    }
}

// Resolve exact threshold bits within bin b.
__global__ __launch_bounds__(1024) void k_scan2(
    const uint32_t* __restrict__ hist2, uint32_t* meta)
{
    __shared__ uint32_t psum[1024];
    __shared__ uint32_t gsuf[64];
    const int t = threadIdx.x;
    const uint32_t k = meta[1];
    const uint32_t b = meta[0];
    const int per = H2_SIZE / 1024;                  // 128 bins/thread
    const int base = t * per;
    uint32_t s = 0;
    for (int i = 0; i < per; i++) s += hist2[base + i];
    psum[t] = s;
    __syncthreads();
    if (t < 64) {
        uint32_t g = 0;
        for (int i = 0; i < 16; i++) g += psum[t * 16 + i];
        uint32_t v = g;
        #pragma unroll
        for (int off = 1; off < 64; off <<= 1) {
            uint32_t o = __shfl_down(v, off);
            if (t + off < 64) v += o;
        }
        gsuf[t] = v;
    }
    __syncthreads();
    const int g = t >> 4;
    uint32_t cum = (g < 63) ? gsuf[g + 1] : 0;
    const int gend = g * 16 + 15;
    for (int j = t + 1; j <= gend; j++) cum += psum[j];
    if (cum < k && k <= cum + psum[t]) {
        uint32_t c = cum;
        for (int i = per - 1; i >= 0; i--) {
            uint32_t h = hist2[base + i];
            c += h;
            if (c >= k) {
                meta[2] = (b << H2_BITS) | (uint32_t)(base + i);
                break;
            }
        }
    }
}

// Accumulate candidates strictly above threshold; full-pass fallback only if
// candidate buffers overflowed (correctness guard, never with this data).
__global__ __launch_bounds__(256) void k_cand(
    const float4* __restrict__ p, const float4* __restrict__ t,
    const float4* __restrict__ w,
    uint32_t* meta, const uint32_t* __restrict__ shard_cnt,
    const uint2* __restrict__ cand, uint32_t cap_per_shard,
    double* __restrict__ sums, int n4)
{
    const uint32_t thr = meta[2];
    const uint32_t overflow = meta[3];
    double lsum = 0.0;
    uint32_t lcnt = 0;
    if (!overflow) {
        for (int sdx = 0; sdx < SHARDS; sdx++) {
            uint32_t cnt = shard_cnt[sdx];
            if (cnt > cap_per_shard) cnt = cap_per_shard;
            const uint2* cs = cand + (size_t)sdx * cap_per_shard;
            for (uint32_t i = blockIdx.x * 256 + threadIdx.x; i < cnt;
                 i += gridDim.x * 256) {
                uint2 e = cs[i];
                if (e.x > thr) {
                    lcnt++;
                    lsum += (double)(__uint_as_float(e.y) * __uint_as_float(e.x));
                }
            }
        }
    } else {
        const uint32_t bb = meta[0];
        const int S = gridDim.x * 256;
        for (int i = blockIdx.x * 256 + threadIdx.x; i < n4; i += S) {
            float4 pv = p[i], tv = t[i], wv = w[i];
            float d[4] = {pv.x - tv.x, pv.y - tv.y, pv.z - tv.z, pv.w - tv.w};
            float wa[4] = {wv.x, wv.y, wv.z, wv.w};
            #pragma unroll
            for (int c = 0; c < 4; c++) {
                float loss = d[c] * d[c] * 0x1p-23f;
                uint32_t bits = __float_as_uint(loss);
                if ((bits >> H2_BITS) == bb && bits > thr) {
                    lcnt++;
                    lsum += (double)(wa[c] * loss);
                }
            }
        }
    }
    #pragma unroll
    for (int off = 32; off; off >>= 1) {
        lsum += __shfl_down(lsum, off);
        lcnt += __shfl_down(lcnt, off);
    }
    __shared__ double sred[4];
    __shared__ uint32_t cred[4];
    const int wid = threadIdx.x >> 6, lane = threadIdx.x & 63;
    if (lane == 0) { sred[wid] = lsum; cred[wid] = lcnt; }
    __syncthreads();
    if (threadIdx.x == 0) {
        double bs = sred[0] + sred[1] + sred[2] + sred[3];
        uint32_t bc = cred[0] + cred[1] + cred[2] + cred[3];
        atomicAdd(&sums[1], bs);
        atomicAdd(&meta[5], bc);
    }
}

__global__ __launch_bounds__(64) void k_final(
    const double* __restrict__ sums, const uint32_t* __restrict__ meta,
    float* __restrict__ out)
{
    if (threadIdx.x == 0 && blockIdx.x == 0) {
        double s = sums[0] + sums[1];
        double c = (double)(meta[4] + meta[5]);
        out[0] = (float)(s / c);
    }
}

extern "C" void kernel_launch(void* const* d_in, const int* in_sizes, int n_in,
                              void* d_out, int out_size, void* d_ws, size_t ws_size,
                              hipStream_t stream) {
    const float* p = (const float*)d_in[0];
    const float* t = (const float*)d_in[1];
    const float* w = (const float*)d_in[2];
    const int* mk = (const int*)d_in[3];
    float* out = (float*)d_out;
    const int n = in_sizes[0];       // 16777216, divisible by 4
    const int n4 = n / 4;

    uint8_t* ws = (uint8_t*)d_ws;
    uint32_t* hist1 = (uint32_t*)ws;
    uint32_t* hist2 = (uint32_t*)(ws + OFF_H2);
    uint32_t* meta  = (uint32_t*)(ws + OFF_META);
    double*   sums  = (double*)(ws + OFF_SUMS);
    uint32_t* shcnt = (uint32_t*)(ws + OFF_SHC);
    uint2*    cand  = (uint2*)(ws + OFF_CAND);
    uint32_t cap_per_shard = 0;
    if (ws_size > OFF_CAND + SHARDS * 8) {
        cap_per_shard = (uint32_t)((ws_size - OFF_CAND) / (8 * SHARDS));
    }

    hipMemsetAsync(d_ws, 0, OFF_CAND, stream);
    k_hist1<<<512, 1024, 0, stream>>>((const float4*)p, (const float4*)t, hist1, n4);
    k_scan1<<<1, 1024, 0, stream>>>(hist1, mk, meta);
    k_main<<<2048, 256, 0, stream>>>((const float4*)p, (const float4*)t,
                                     (const float4*)w, meta, hist2, sums, shcnt,
                                     cand, cap_per_shard, n4);
    k_scan2<<<1, 1024, 0, stream>>>(hist2, meta);
    k_cand<<<256, 256, 0, stream>>>((const float4*)p, (const float4*)t,
                                    (const float4*)w, meta, shcnt, cand,
                                    cap_per_shard, sums, n4);
    k_final<<<1, 64, 0, stream>>>(sums, meta, out);
}